// Round 1
// baseline (480.313 us; speedup 1.0000x reference)
//
#include <hip/hip_runtime.h>

// IncConv (version==3): out = zeros except 64x64 patch at [48,112)x[48,112)
// holding conv3x3(in, w, pad=1, stride=1) + bias.
// B=16, C_in=C_out=64, H=W=224. Patch is interior -> no bounds checks.

#define BATCH 16
#define CH    64
#define HW    224
#define PR    48
#define PC    48
#define PH    64
#define PW    64

#define CI_CHUNK 8
#define LDS_RS   36            // LDS row stride in dwords (16B aligned, conflict-min)
#define LDS_SS   (34 * LDS_RS) // slice stride = 1224 dwords
#define NCONV    256
#define NZERO    512
#define THREADS  512

__global__ __launch_bounds__(THREADS, 4)
void inc_conv_fused(const float* __restrict__ in, const float* __restrict__ wgt,
                    const float* __restrict__ bias, float* __restrict__ out) {
    __shared__ float lds[CI_CHUNK * LDS_SS];
    const int bid = blockIdx.x;
    const int tid = threadIdx.x;

    if (bid >= NCONV) {
        // ---------------- zero-fill blocks (skip the conv patch) ----------------
        const int NT4 = BATCH * CH * HW * HW / 4;   // 12,845,056 float4 stores
        const int ZTT = NZERO * THREADS;            // 262,144 threads -> 49 iters each
        float4 z = make_float4(0.f, 0.f, 0.f, 0.f);
        float4* o4 = (float4*)out;
        for (int i = (bid - NCONV) * THREADS + tid; i < NT4; i += ZTT) {
            int p  = i % (HW * HW / 4);   // position within one 224x224 plane (f4 units)
            int h  = p / (HW / 4);
            int w0 = (p - h * (HW / 4)) * 4;
            bool inpatch = (h >= PR) & (h < PR + PH) & (w0 >= PC) & (w0 < PC + PW);
            if (!inpatch) o4[i] = z;
        }
        return;
    }

    // ---------------- conv blocks ----------------
    // bid = b*16 + cog*4 + sp ; block tile = 16 c_out x 32x32 spatial
    const int b   = bid >> 4;
    const int cog = (bid >> 2) & 3;
    const int sp  = bid & 3;
    const int ty  = sp >> 1, tx = sp & 1;

    const int co_set = tid >> 7;          // 0..3 (wave-pair uniform)
    const int co0    = cog * 16 + co_set * 4;
    const int sp_id  = tid & 127;
    const int r      = sp_id >> 2;        // 0..31 output row within tile
    const int q      = sp_id & 3;
    const int w0     = q * 8;             // 8 consecutive output cols per thread

    const int row0 = PR + ty * 32;
    const int col0 = PC + tx * 32;
    const int gr0  = row0 - 1;            // staged input origin (row)
    const int gc0  = col0 - 1;            // staged input origin (col)

    float acc[4][8];
    #pragma unroll
    for (int c = 0; c < 4; ++c)
        #pragma unroll
        for (int w = 0; w < 8; ++w) acc[c][w] = 0.f;

    const int co0u = __builtin_amdgcn_readfirstlane(co0);   // force SGPR weight path

    for (int c0 = 0; c0 < CH; c0 += CI_CHUNK) {
        __syncthreads();   // protect lds reuse from previous chunk's readers
        // stage CI_CHUNK slices of 34x34 input (halo included)
        for (int e = tid; e < CI_CHUNK * 34 * 34; e += THREADS) {
            int s   = e / (34 * 34);
            int rem = e - s * (34 * 34);
            int rr  = rem / 34;
            int cc  = rem - rr * 34;
            lds[s * LDS_SS + rr * LDS_RS + cc] =
                in[(b * CH + c0 + s) * (HW * HW) + (gr0 + rr) * HW + gc0 + cc];
        }
        __syncthreads();

        for (int s = 0; s < CI_CHUNK; ++s) {
            const int ci = c0 + s;
            // wave-uniform scalar weight loads: w[co][ci][kh][kw], co stride = 64*9
            float wv[4][9];
            const float* wp = wgt + (size_t)co0u * (CH * 9) + ci * 9;
            #pragma unroll
            for (int c = 0; c < 4; ++c)
                #pragma unroll
                for (int k = 0; k < 9; ++k)
                    wv[c][k] = wp[c * (CH * 9) + k];

            const float* lrow = &lds[s * LDS_SS + r * LDS_RS + w0];
            #pragma unroll
            for (int kh = 0; kh < 3; ++kh) {
                // 12 floats cover cols w0-1..w0+9 (input coords) for kw=0..2
                const float4* lp = (const float4*)(lrow + kh * LDS_RS);
                float4 f0 = lp[0], f1 = lp[1], f2 = lp[2];
                float f[12] = { f0.x, f0.y, f0.z, f0.w,
                                f1.x, f1.y, f1.z, f1.w,
                                f2.x, f2.y, f2.z, f2.w };
                #pragma unroll
                for (int c = 0; c < 4; ++c)
                    #pragma unroll
                    for (int kw = 0; kw < 3; ++kw) {
                        const float ws = wv[c][kh * 3 + kw];
                        #pragma unroll
                        for (int w = 0; w < 8; ++w)
                            acc[c][w] = fmaf(f[w + kw], ws, acc[c][w]);
                    }
            }
        }
    }

    // epilogue: bias + store 2x float4 per c_out (col0+w0 is 8-aligned)
    #pragma unroll
    for (int c = 0; c < 4; ++c) {
        const float bv = bias[co0u + c];
        float4 v0 = make_float4(acc[c][0] + bv, acc[c][1] + bv,
                                acc[c][2] + bv, acc[c][3] + bv);
        float4 v1 = make_float4(acc[c][4] + bv, acc[c][5] + bv,
                                acc[c][6] + bv, acc[c][7] + bv);
        float4* op = (float4*)&out[(b * CH + co0 + c) * (HW * HW)
                                   + (row0 + r) * HW + col0 + w0];
        op[0] = v0;
        op[1] = v1;
    }
}

extern "C" void kernel_launch(void* const* d_in, const int* in_sizes, int n_in,
                              void* d_out, int out_size, void* d_ws, size_t ws_size,
                              hipStream_t stream) {
    const float* in   = (const float*)d_in[0];
    const float* wgt  = (const float*)d_in[1];
    const float* bias = (const float*)d_in[2];
    float* out = (float*)d_out;
    dim3 grid(NCONV + NZERO);
    dim3 block(THREADS);
    inc_conv_fused<<<grid, block, 0, stream>>>(in, wgt, bias, out);
}

// Round 2
// 457.776 us; speedup vs baseline: 1.0492x; 1.0492x over previous
//
#include <hip/hip_runtime.h>
#include <stdint.h>

// IncConv (version==3): out = zeros except 64x64 patch at [48,112)^2 holding
// conv3x3(in, w, pad=1, stride=1) + bias.  B=16, C_in=C_out=64, H=W=224.
// Implicit GEMM on bf16 MFMA with 3-term hi/lo split for fp32 accuracy:
//   D = Ah*Bh + Ah*Bl + Al*Bh   (Al*Bl ~ 2^-18, dropped)
// M = (b, pr, pc) = 65536, N = co = 64, K = (tap, ci) = 576.
// Zero-fill fused into the same blocks, issued after the last staging loads.

#define BATCH 16
#define CI    64
#define CO    64
#define HW    224
#define PR0   48
#define PC0   48
#define PATCH 64

#define THREADS 512
#define NBLK    256

// LDS layout (units: shorts/bf16)
#define A_ROWS 6
#define A_COLS 66
#define A_CELL 40                         // 32 ci + 8 pad -> 80 B cell, bank-shift 20
#define A_SIZE (A_ROWS * A_COLS * A_CELL) // 15840
#define B_KPAD 296                        // 9 taps * 32 ci = 288, +8 pad -> 592 B row
#define B_SIZE (CO * B_KPAD)              // 18944
#define LDS_SHORTS (2 * (A_SIZE + B_SIZE))
#define LDS_BYTES  (LDS_SHORTS * 2)       // 139136 B

typedef __attribute__((ext_vector_type(8))) short short8v;
typedef __attribute__((ext_vector_type(4))) float f32x4;

union fu32 { float f; uint32_t u; };

__device__ __forceinline__ uint16_t f2bf(float x) {
    fu32 c; c.f = x;
    return (uint16_t)((c.u + 0x7FFFu + ((c.u >> 16) & 1u)) >> 16);  // RNE
}
__device__ __forceinline__ float bf2f(uint16_t h) {
    fu32 c; c.u = ((uint32_t)h) << 16; return c.f;
}

__global__ __launch_bounds__(THREADS, 1)
void inc_conv_mfma(const float* __restrict__ in, const float* __restrict__ wgt,
                   const float* __restrict__ bias, float* __restrict__ out) {
    extern __shared__ short smem[];
    short* Ah = smem;
    short* Al = smem + A_SIZE;
    short* Bh = smem + 2 * A_SIZE;
    short* Bl = smem + 2 * A_SIZE + B_SIZE;

    const int bid  = blockIdx.x;
    const int tid  = threadIdx.x;
    const int b    = bid >> 4;    // batch
    const int band = bid & 15;    // 4-row band of the 64-row patch

    const int lane = tid & 63;
    const int wv   = tid >> 6;    // wave 0..7
    const int l15  = lane & 15;
    const int kb   = lane >> 4;   // k-block 0..3
    const int prl  = wv >> 1;     // wave's patch row within band (0..3)
    const int pcb  = (wv & 1) << 5; // wave's patch col base (0 / 32)

    const int gr = PR0 - 1 + (band << 2); // staged input origin row (47..107)
    const int gc = PC0 - 1;               // staged input origin col (47)

    // preload bias now so no global LOADS remain after the zero-store burst
    float bias_v[4];
    #pragma unroll
    for (int nf = 0; nf < 4; ++nf) bias_v[nf] = bias[nf * 16 + l15];

    f32x4 acc[2][4];
    #pragma unroll
    for (int mf = 0; mf < 2; ++mf)
        #pragma unroll
        for (int nf = 0; nf < 4; ++nf)
            acc[mf][nf] = (f32x4){0.f, 0.f, 0.f, 0.f};

    const int aBase = (prl * A_COLS + pcb + l15) * A_CELL + kb * 8;
    const int bBase = l15 * B_KPAD + kb * 8;

    for (int chunk = 0; chunk < 2; ++chunk) {
        const int ci0 = chunk << 5;   // ci chunk of 32
        if (chunk) __syncthreads();   // previous chunk's readers done

        // ---- stage A: 32 ci x 6 rows x 66 cols, split hi/lo ----
        for (int e = tid; e < 32 * A_ROWS * A_COLS; e += THREADS) {
            int s   = e / (A_ROWS * A_COLS);
            int rem = e - s * (A_ROWS * A_COLS);
            int r   = rem / A_COLS;
            int c   = rem - r * A_COLS;
            float x = in[((b * CI + ci0 + s) * HW + gr + r) * HW + gc + c];
            uint16_t h = f2bf(x);
            uint16_t l = f2bf(x - bf2f(h));
            int idx = (r * A_COLS + c) * A_CELL + s;
            Ah[idx] = (short)h;
            Al[idx] = (short)l;
        }
        // ---- stage B: w[n][ci0+cil][t] -> B[n][t*32+cil], split hi/lo ----
        for (int e = tid; e < CO * 32 * 9; e += THREADS) {
            int n   = e / 288;
            int rem = e - n * 288;
            int cil = rem / 9;
            int t   = rem - cil * 9;
            float x = wgt[(n * CI + ci0 + cil) * 9 + t];
            uint16_t h = f2bf(x);
            uint16_t l = f2bf(x - bf2f(h));
            int idx = n * B_KPAD + t * 32 + cil;
            Bh[idx] = (short)h;
            Bl[idx] = (short)l;
        }
        __syncthreads();

        if (chunk == 1) {
            // ---- fused zero-fill: issue now, drains under MFMA + kernel end.
            // No global loads after this point (bias preloaded), so no
            // compiler vmcnt(0) ever waits on this 200 MB store stream.
            const int gtid = bid * THREADS + tid;
            const int NT4  = BATCH * CO * HW * HW / 4;   // 12,845,056 float4
            float4* o4 = (float4*)out;
            const float4 z = make_float4(0.f, 0.f, 0.f, 0.f);
            for (int i = gtid; i < NT4; i += NBLK * THREADS) {
                int p  = i % (HW * HW / 4);   // pos in one plane (f4 units)
                int h  = p / (HW / 4);
                int w4 = p - h * (HW / 4);
                bool inpatch = (h >= PR0) && (h < PR0 + PATCH) &&
                               (w4 >= PC0 / 4) && (w4 < (PC0 + PATCH) / 4);
                if (!inpatch) o4[i] = z;
            }
        }

        // ---- MFMA over 9 taps, K-step = (tap, 32 ci) ----
        #pragma unroll
        for (int t = 0; t < 9; ++t) {
            const int kh = t / 3, kw = t - kh * 3;
            short8v ah[2], al[2], bh[4], bl[4];
            #pragma unroll
            for (int mf = 0; mf < 2; ++mf) {
                const int off = aBase + (kh * A_COLS + mf * 16 + kw) * A_CELL;
                ah[mf] = *(const short8v*)(Ah + off);
                al[mf] = *(const short8v*)(Al + off);
            }
            #pragma unroll
            for (int nf = 0; nf < 4; ++nf) {
                const int off = bBase + nf * 16 * B_KPAD + t * 32;
                bh[nf] = *(const short8v*)(Bh + off);
                bl[nf] = *(const short8v*)(Bl + off);
            }
            #pragma unroll
            for (int mf = 0; mf < 2; ++mf)
                #pragma unroll
                for (int nf = 0; nf < 4; ++nf) {
                    acc[mf][nf] = __builtin_amdgcn_mfma_f32_16x16x32_bf16(
                        ah[mf], bh[nf], acc[mf][nf], 0, 0, 0);
                    acc[mf][nf] = __builtin_amdgcn_mfma_f32_16x16x32_bf16(
                        ah[mf], bl[nf], acc[mf][nf], 0, 0, 0);
                    acc[mf][nf] = __builtin_amdgcn_mfma_f32_16x16x32_bf16(
                        al[mf], bh[nf], acc[mf][nf], 0, 0, 0);
                }
        }
    }

    // ---- epilogue: C/D layout col=lane&15 (N), row=(lane>>4)*4+reg (M) ----
    // M = pr*64 + pc; reg walks 4 consecutive pc -> aligned float4 store.
    const int orow = PR0 + (band << 2) + prl;
    #pragma unroll
    for (int nf = 0; nf < 4; ++nf) {
        const int co = nf * 16 + l15;
        const float bv = bias_v[nf];
        #pragma unroll
        for (int mf = 0; mf < 2; ++mf) {
            const int ocol = PC0 + pcb + mf * 16 + kb * 4;
            f32x4 v = acc[mf][nf];
            float4 st = make_float4(v[0] + bv, v[1] + bv, v[2] + bv, v[3] + bv);
            *(float4*)&out[((b * CO + co) * HW + orow) * HW + ocol] = st;
        }
    }
}

extern "C" void kernel_launch(void* const* d_in, const int* in_sizes, int n_in,
                              void* d_out, int out_size, void* d_ws, size_t ws_size,
                              hipStream_t stream) {
    const float* in   = (const float*)d_in[0];
    const float* wgt  = (const float*)d_in[1];
    const float* bias = (const float*)d_in[2];
    float* out = (float*)d_out;
    // >64 KB dynamic LDS opt-in (host-side, idempotent; safe under capture)
    hipFuncSetAttribute((const void*)inc_conv_mfma,
                        hipFuncAttributeMaxDynamicSharedMemorySize, LDS_BYTES);
    inc_conv_mfma<<<NBLK, THREADS, LDS_BYTES, stream>>>(in, wgt, bias, out);
}